// Round 4
// baseline (354.836 us; speedup 1.0000x reference)
//
#include <hip/hip_runtime.h>

#define T_LEN  2048
#define NCH    4096     // chains (B)
#define CH     64       // chunk length (timesteps per output chunk)
#define NCHUNK (T_LEN / CH)
#define WARM   256      // warm-up steps before each chunk (chunk 0: exact from zero)
#define TK     4        // timesteps per LDS tile (4 KB per tile)
#define NBUF   4        // ring depth: 16 KB LDS total -> still 8 blocks/CU
#define WPC    64       // chains per wave (= block size, 1 wave per block)

__device__ __forceinline__ float clampf(float x, float lo, float hi) {
    return fminf(fmaxf(x, lo), hi);
}

struct Params {
    float insc, C, S, sub, crak, rk, kr, lg, ls, invS, eca;
};

__device__ __forceinline__ Params mkparams(
    const float* pINSC, const float* pCOEFF, const float* pSQ, const float* pSMSC,
    const float* pSUB, const float* pCRAK, const float* pRecK, const float* pKr,
    const float* pLG, const float* pLS)
{
    Params pr;
    pr.insc = clampf(pINSC[0] * 5.f,   0.5f,   5.f);
    pr.C    = clampf(pCOEFF[0] * 400.f, 50.f,  400.f);
    float q = clampf(pSQ[0] * 6.f,     0.f,    6.f);
    pr.S    = clampf(pSMSC[0] * 500.f, 50.f,   500.f);
    pr.sub  = clampf(pSUB[0],          0.f,    1.f);
    pr.crak = clampf(pCRAK[0],         0.f,    1.f);
    pr.rk   = clampf(pRecK[0] * 0.3f,  0.003f, 0.3f);
    pr.kr   = clampf(pKr[0] * 0.1f,    0.01f,  0.1f);
    pr.lg   = clampf(pLG[0] * 0.1f,    0.001f, 0.1f);
    pr.ls   = clampf(pLS[0] * 10.f,    0.01f,  10.f);
    pr.invS = 1.0f / pr.S;
    pr.eca  = -q * pr.invS;
    return pr;
}

// HBM -> LDS direct (no VGPR round trip). LDS dest is wave-uniform base;
// HW writes lane i at dst + i*16. Global src address is per-lane.
__device__ __forceinline__ void gload_lds16(const float4* g, float4* l) {
    __builtin_amdgcn_global_load_lds(
        (const __attribute__((address_space(1))) void*)(g),
        (__attribute__((address_space(3))) void*)(l),
        16, 0, 0);
}

// One recurrence step. OUT=true additionally computes the fused post-pass Q.
template <bool OUT>
__device__ __forceinline__ float step_one(const Params& pr, const float4& xv,
                                          float& sms, float& gw, float& rs)
{
    const float p = xv.x, pet = xv.y, rsmax = xv.z, area = xv.w;

    const float INT  = fminf(fminf(pr.insc, pet), p);
    const float INR  = p - INT;
    const float smsc  = fminf(fmaxf(sms, 0.f), pr.S);
    const float ratio = smsc * pr.invS;
    const float infil = pr.C * __expf(pr.eca * smsc);
    const float RMO   = fminf(infil, INR);
    const float IRUN  = INR - RMO;
    const float SRUN  = pr.sub * ratio * RMO;
    const float REC   = pr.crak * ratio * (RMO - SRUN);
    const float SMF   = (RMO - SRUN) - REC;
    const float POT   = pet - INT;              // INT <= pet always -> max(.,0) redundant
    const float ETS   = fminf(POT, 10.f * ratio);
    const float nsms  = smsc + (SMF - ETS);
    const float RECn  = REC + fmaxf(nsms - pr.S, 0.f);
    const float BAS   = pr.rk * fmaxf(gw, 0.f);
    const float ngw   = (gw - pr.lg) + (RECn - BAS);
    const float inflow = (IRUN + SRUN + BAS) * area;
    const float rinv   = __builtin_amdgcn_rcpf(rsmax);
    const float xr     = (rs + inflow) - rsmax;
    const float Qor    = fmaxf(xr, 0.f);
    const float rrt    = rs * rinv;
    const float Qir    = (xr > 0.f) ? (pr.kr * rsmax)
                                    : (pr.kr * rs * (rrt * __builtin_amdgcn_sqrtf(rrt)));
    const float nrs    = rs + ((inflow - Qor) - Qir);

    float q = 0.f;
    if constexpr (OUT) {
        // fused post-pass (valid for t>=1; t==0 fixed by hirnn_t0_kernel)
        const float xq   = (nrs + inflow) - rsmax;
        const float Qor2 = fmaxf(xq, 0.f);
        const float r2   = nrs * rinv;
        const float Qir2 = (xq > 0.f) ? (pr.kr * rsmax)
                                      : (pr.kr * nrs * (r2 * __builtin_amdgcn_sqrtf(r2)));
        const float oma  = 1.f - area;
        const float dra  = (SRUN + IRUN) * oma + Qir2 + Qor2 - pr.ls;
        q = fmaxf(fmaxf(dra, 0.f) + BAS * oma, 0.f);
    }

    sms = nsms; gw = ngw; rs = nrs;
    return q;
}

// ---------------- main chunked scan kernel ----------------
// 1 wave per block, 64 chains per wave. Per 4-step tile the wave stages
// [64 chains x 4 steps] HBM->LDS via 4 global_load_lds (each = 16 contiguous
// 64B segments), 4-deep ring buffer, pipelined with counted s_waitcnt vmcnt:
// steady state keeps 3 tiles (12 loads) in flight -> ~1400-2800 cycles of
// latency cover. No __syncthreads anywhere (staging is wave-local).
// Step index is XOR-swizzled on the GLOBAL source address (LDS dest is linear):
// stored step for (chain c, slot j) is j ^ ((c>>1)&3), which makes the per-step
// wave ds_read_b128 spread 8 lanes per bank-quad in distinct rows (conflict-free).
__global__ __launch_bounds__(64)
void hirnn_chunk_kernel(const float* __restrict__ inp,
                        const float* __restrict__ pINSC, const float* __restrict__ pCOEFF,
                        const float* __restrict__ pSQ,   const float* __restrict__ pSMSC,
                        const float* __restrict__ pSUB,  const float* __restrict__ pCRAK,
                        const float* __restrict__ pRecK, const float* __restrict__ pKr,
                        const float* __restrict__ pLG,   const float* __restrict__ pLS,
                        float* __restrict__ out, float* __restrict__ ws)
{
    __shared__ float4 buf[NBUF][WPC * TK];     // 4 x 4 KB = 16 KB

    const int l     = threadIdx.x;             // lane 0..63
    const int blk   = blockIdx.x;
    const int chunk = blk & (NCHUNK - 1);      // fast index: consecutive blocks get
    const int cgrp  = blk >> 5;                //   different chunk lengths (balance)
    const int cbase = cgrp * WPC;
    const int chain = cbase + l;

    const Params pr = mkparams(pINSC, pCOEFF, pSQ, pSMSC, pSUB, pCRAK, pRecK, pKr, pLG, pLS);

    // Staging map, instruction k (k=0..3): lane l covers
    //   chain = cbase + 16k + (l>>2), global step = t0 + ((l&3) ^ ((l>>3)&3))
    // -> every aligned 4-lane group covers one full 64B segment (16 segs/inst).
    const float4* __restrict__ gl =
        reinterpret_cast<const float4*>(inp)
        + (size_t)(cbase + (l >> 2)) * T_LEN + ((l & 3) ^ ((l >> 3) & 3));

    float4* __restrict__ qout = reinterpret_cast<float4*>(out + (size_t)chain * T_LEN);

    const int t_start = chunk * CH;
    const int t_warm  = (t_start >= WARM) ? (t_start - WARM) : 0;
    const int t_end   = t_start + CH;

    float sms = 0.f, gw = 0.f, rs = 0.f;       // warm-start from zero state

    auto issue_tile = [&](float4* dst, int t0) {
#pragma unroll
        for (int k = 0; k < TK; ++k)
            gload_lds16(gl + (size_t)(k * 16) * T_LEN + t0, dst + k * WPC);
    };

    // prologue: fill 3 of the 4 ring slots (12 loads in flight)
    issue_tile(&buf[0][0], t_warm);
    issue_tile(&buf[1][0], t_warm + TK);
    issue_tile(&buf[2][0], t_warm + 2 * TK);

    const int rbase = l * TK;                  // own chain's row base (float4 units)
    const int rx    = (l >> 1) & 3;            // read-side XOR

    int p = 0;
    for (int t0 = t_warm; t0 < t_end; t0 += TK, p = (p + 1) & 3) {
        const int t_pre = t0 + 3 * TK;
        if (t_pre < t_end) {
            issue_tile(&buf[(p + 3) & 3][0], t_pre);      // keep 3 tiles ahead
            asm volatile("s_waitcnt vmcnt(12)" ::: "memory");
        } else {
            const int nrem = (t_end - t0) >> 2;           // tiles incl current: 1..3
            if (nrem == 3)      asm volatile("s_waitcnt vmcnt(8)" ::: "memory");
            else if (nrem == 2) asm volatile("s_waitcnt vmcnt(4)" ::: "memory");
            else                asm volatile("s_waitcnt vmcnt(0)" ::: "memory");
        }
        __builtin_amdgcn_sched_barrier(0);

        const float4* bp = &buf[p][0];
        float4 x[TK];
#pragma unroll
        for (int s = 0; s < TK; ++s)
            x[s] = bp[rbase + (s ^ rx)];

        if (t0 < t_start) {                    // warm-up: state only
#pragma unroll
            for (int s = 0; s < TK; ++s) step_one<false>(pr, x[s], sms, gw, rs);
        } else {                               // output phase
            float q[TK];
#pragma unroll
            for (int s = 0; s < TK; ++s) q[s] = step_one<true>(pr, x[s], sms, gw, rs);
            float4 w;
            w.x = q[0]; w.y = q[1]; w.z = q[2]; w.w = q[3];
            qout[t0 / 4] = w;
        }
    }

    if (chunk == NCHUNK - 1) {                 // final state for the t==0 fix-up
        ws[chain * 2 + 0] = sms;
        ws[chain * 2 + 1] = gw;
    }
}

// ---------------- t == 0 fix-up kernel ----------------
// Q[b,0] uses SMS1=final sms, GW1=final gw, RS=rs after step 0 (exact: zero start state).
__global__ __launch_bounds__(256)
void hirnn_t0_kernel(const float* __restrict__ inp,
                     const float* __restrict__ pINSC, const float* __restrict__ pCOEFF,
                     const float* __restrict__ pSQ,   const float* __restrict__ pSMSC,
                     const float* __restrict__ pSUB,  const float* __restrict__ pCRAK,
                     const float* __restrict__ pRecK, const float* __restrict__ pKr,
                     const float* __restrict__ pLG,   const float* __restrict__ pLS,
                     const float* __restrict__ ws, float* __restrict__ out)
{
    const int b = blockIdx.x * blockDim.x + threadIdx.x;
    if (b >= NCH) return;

    const Params pr = mkparams(pINSC, pCOEFF, pSQ, pSMSC, pSUB, pCRAK, pRecK, pKr, pLG, pLS);

    const float4 x0 = reinterpret_cast<const float4*>(inp)[(size_t)b * T_LEN];
    const float p = x0.x, pet = x0.y, rsmax = x0.z, area = x0.w;

    const float INT = fminf(fminf(pr.insc, pet), p);
    const float INR = p - INT;

    // RS after step 0, exact from zero state: sms=0 -> ratio=0, infil=C; gw=0 -> BAS0=0
    const float RMO0   = fminf(pr.C, INR);
    const float IRUN0  = INR - RMO0;
    const float infl0  = IRUN0 * area;
    const float xr0    = infl0 - rsmax;
    const float Qor0   = fmaxf(xr0, 0.f);
    const float Qir0   = (xr0 > 0.f) ? (pr.kr * rsmax) : 0.f;   // rs=0 -> power term = 0
    const float rs0    = infl0 - Qor0 - Qir0;

    // post-pass with SMS1 = final sms, GW1 = final gw
    const float smsF  = ws[b * 2 + 0];
    const float gwF   = ws[b * 2 + 1];
    const float smsc  = fminf(fmaxf(smsF, 0.f), pr.S);
    const float ratio = smsc * pr.invS;
    const float infil = pr.C * __expf(pr.eca * smsc);
    const float RMO   = fminf(infil, INR);
    const float IRUN  = INR - RMO;
    const float SRUN  = pr.sub * ratio * RMO;
    const float BAS   = pr.rk * fmaxf(gwF, 0.f);

    const float inflow = (IRUN + SRUN + BAS) * area;
    const float rinv   = __builtin_amdgcn_rcpf(rsmax);
    const float xq     = (rs0 + inflow) - rsmax;
    const float Qor2   = fmaxf(xq, 0.f);
    const float r2     = rs0 * rinv;
    const float Qir2   = (xq > 0.f) ? (pr.kr * rsmax)
                                    : (pr.kr * rs0 * (r2 * __builtin_amdgcn_sqrtf(r2)));
    const float oma    = 1.f - area;
    const float dra    = (SRUN + IRUN) * oma + Qir2 + Qor2 - pr.ls;
    out[(size_t)b * T_LEN] = fmaxf(fmaxf(dra, 0.f) + BAS * oma, 0.f);
}

extern "C" void kernel_launch(void* const* d_in, const int* in_sizes, int n_in,
                              void* d_out, int out_size, void* d_ws, size_t ws_size,
                              hipStream_t stream) {
    const float* inp = (const float*)d_in[0];
    float* out = (float*)d_out;
    float* ws  = (float*)d_ws;   // 4096 * 2 floats

    const int blocks = NCHUNK * (NCH / WPC);    // 32 x 64 = 2048 blocks, 1 wave each
    hirnn_chunk_kernel<<<blocks, WPC, 0, stream>>>(
        inp,
        (const float*)d_in[1], (const float*)d_in[2], (const float*)d_in[3],
        (const float*)d_in[4], (const float*)d_in[5], (const float*)d_in[6],
        (const float*)d_in[7], (const float*)d_in[8], (const float*)d_in[9],
        (const float*)d_in[10],
        out, ws);

    hirnn_t0_kernel<<<NCH / 256, 256, 0, stream>>>(
        inp,
        (const float*)d_in[1], (const float*)d_in[2], (const float*)d_in[3],
        (const float*)d_in[4], (const float*)d_in[5], (const float*)d_in[6],
        (const float*)d_in[7], (const float*)d_in[8], (const float*)d_in[9],
        (const float*)d_in[10],
        ws, out);
}

// Round 5
// 315.347 us; speedup vs baseline: 1.1252x; 1.1252x over previous
//
#include <hip/hip_runtime.h>

#define T_LEN  2048
#define NCH    4096     // chains (B)
#define CH     64       // chunk length (timesteps per output chunk)
#define NCHUNK (T_LEN / CH)
#define WARM   256      // warm-up steps before each chunk (chunk 0: exact from zero)
#define TK     4        // timesteps per LDS tile (4 KB per tile)
#define NBUF   4        // ring depth: 16 KB LDS total -> 8 blocks/CU (grid fully resident)
#define WPC    64       // chains per wave (= block size, 1 wave per block)

__device__ __forceinline__ float clampf(float x, float lo, float hi) {
    return fminf(fmaxf(x, lo), hi);
}

struct Params {
    float insc, C, S, sub, crak, rk, kr, lg, ls, invS, eca;
};

__device__ __forceinline__ Params mkparams(
    const float* pINSC, const float* pCOEFF, const float* pSQ, const float* pSMSC,
    const float* pSUB, const float* pCRAK, const float* pRecK, const float* pKr,
    const float* pLG, const float* pLS)
{
    Params pr;
    pr.insc = clampf(pINSC[0] * 5.f,   0.5f,   5.f);
    pr.C    = clampf(pCOEFF[0] * 400.f, 50.f,  400.f);
    float q = clampf(pSQ[0] * 6.f,     0.f,    6.f);
    pr.S    = clampf(pSMSC[0] * 500.f, 50.f,   500.f);
    pr.sub  = clampf(pSUB[0],          0.f,    1.f);
    pr.crak = clampf(pCRAK[0],         0.f,    1.f);
    pr.rk   = clampf(pRecK[0] * 0.3f,  0.003f, 0.3f);
    pr.kr   = clampf(pKr[0] * 0.1f,    0.01f,  0.1f);
    pr.lg   = clampf(pLG[0] * 0.1f,    0.001f, 0.1f);
    pr.ls   = clampf(pLS[0] * 10.f,    0.01f,  10.f);
    pr.invS = 1.0f / pr.S;
    pr.eca  = -q * pr.invS;
    return pr;
}

// HBM -> LDS direct (no VGPR round trip). LDS dest is wave-uniform base;
// HW writes lane i at dst + i*16. Global src address is per-lane.
__device__ __forceinline__ void gload_lds16(const float4* g, float4* l) {
    __builtin_amdgcn_global_load_lds(
        (const __attribute__((address_space(1))) void*)(g),
        (__attribute__((address_space(3))) void*)(l),
        16, 0, 0);
}

// One recurrence step. OUT=true additionally computes the fused post-pass Q.
template <bool OUT>
__device__ __forceinline__ float step_one(const Params& pr, const float4& xv,
                                          float& sms, float& gw, float& rs)
{
    const float p = xv.x, pet = xv.y, rsmax = xv.z, area = xv.w;

    const float INT  = fminf(fminf(pr.insc, pet), p);
    const float INR  = p - INT;
    const float smsc  = fminf(fmaxf(sms, 0.f), pr.S);
    const float ratio = smsc * pr.invS;
    const float infil = pr.C * __expf(pr.eca * smsc);
    const float RMO   = fminf(infil, INR);
    const float IRUN  = INR - RMO;
    const float SRUN  = pr.sub * ratio * RMO;
    const float REC   = pr.crak * ratio * (RMO - SRUN);
    const float SMF   = (RMO - SRUN) - REC;
    const float POT   = pet - INT;              // INT <= pet always -> max(.,0) redundant
    const float ETS   = fminf(POT, 10.f * ratio);
    const float nsms  = smsc + (SMF - ETS);
    const float RECn  = REC + fmaxf(nsms - pr.S, 0.f);
    const float BAS   = pr.rk * fmaxf(gw, 0.f);
    const float ngw   = (gw - pr.lg) + (RECn - BAS);
    const float inflow = (IRUN + SRUN + BAS) * area;
    const float rinv   = __builtin_amdgcn_rcpf(rsmax);
    const float xr     = (rs + inflow) - rsmax;
    const float Qor    = fmaxf(xr, 0.f);
    const float rrt    = rs * rinv;
    const float Qir    = (xr > 0.f) ? (pr.kr * rsmax)
                                    : (pr.kr * rs * (rrt * __builtin_amdgcn_sqrtf(rrt)));
    const float nrs    = rs + ((inflow - Qor) - Qir);

    float q = 0.f;
    if constexpr (OUT) {
        // fused post-pass (valid for t>=1; t==0 fixed by hirnn_t0_kernel)
        const float xq   = (nrs + inflow) - rsmax;
        const float Qor2 = fmaxf(xq, 0.f);
        const float r2   = nrs * rinv;
        const float Qir2 = (xq > 0.f) ? (pr.kr * rsmax)
                                      : (pr.kr * nrs * (r2 * __builtin_amdgcn_sqrtf(r2)));
        const float oma  = 1.f - area;
        const float dra  = (SRUN + IRUN) * oma + Qir2 + Qor2 - pr.ls;
        q = fmaxf(fmaxf(dra, 0.f) + BAS * oma, 0.f);
    }

    sms = nsms; gw = ngw; rs = nrs;
    return q;
}

// ---------------- main chunked scan kernel ----------------
// 1 wave per block, 64 chains per wave. Per 4-step tile the wave stages
// [64 chains x 4 steps] HBM->LDS via 4 global_load_lds, 4-deep ring buffer,
// pipelined with counted s_waitcnt vmcnt: steady state keeps 3 tiles
// (12 loads) in flight. No __syncthreads anywhere (staging is wave-local).
//
// Block decode: blk = chunk*64 + cgrp. The 5 chunk-windows overlapping a given
// input line live in blocks spaced 64 apart -> same XCD (64 % 8 == 0) and
// co-resident (grid = 2048 one-wave blocks = 8 waves/CU, fully resident)
// -> L2 absorbs the warm-up re-reads. (R4's decode flip broke this: +40% FETCH.)
//
// Step index is XOR-swizzled on the GLOBAL source address (LDS dest is linear):
// stored step for (chain c, slot j) is j ^ ((c>>1)&3), so the per-step
// wave ds_read_b128 spreads 8 lanes per bank-quad in distinct rows.
__global__ __launch_bounds__(64)
void hirnn_chunk_kernel(const float* __restrict__ inp,
                        const float* __restrict__ pINSC, const float* __restrict__ pCOEFF,
                        const float* __restrict__ pSQ,   const float* __restrict__ pSMSC,
                        const float* __restrict__ pSUB,  const float* __restrict__ pCRAK,
                        const float* __restrict__ pRecK, const float* __restrict__ pKr,
                        const float* __restrict__ pLG,   const float* __restrict__ pLS,
                        float* __restrict__ out, float* __restrict__ ws)
{
    __shared__ float4 buf[NBUF][WPC * TK];     // 4 x 4 KB = 16 KB

    const int l     = threadIdx.x;             // lane 0..63
    const int blk   = blockIdx.x;
    const int chunk = blk >> 6;                // 64 chain-groups per chunk
    const int cgrp  = blk & 63;
    const int cbase = cgrp * WPC;
    const int chain = cbase + l;

    const Params pr = mkparams(pINSC, pCOEFF, pSQ, pSMSC, pSUB, pCRAK, pRecK, pKr, pLG, pLS);

    // Staging map, instruction k (k=0..3): lane l covers
    //   chain = cbase + 16k + (l>>2), global step = t0 + ((l&3) ^ ((l>>3)&3))
    // -> every aligned 4-lane group covers one full 64B segment (16 segs/inst).
    const float4* __restrict__ gl =
        reinterpret_cast<const float4*>(inp)
        + (size_t)(cbase + (l >> 2)) * T_LEN + ((l & 3) ^ ((l >> 3) & 3));

    float4* __restrict__ qout = reinterpret_cast<float4*>(out + (size_t)chain * T_LEN);

    const int t_start = chunk * CH;
    const int t_warm  = (t_start >= WARM) ? (t_start - WARM) : 0;
    const int t_end   = t_start + CH;

    float sms = 0.f, gw = 0.f, rs = 0.f;       // warm-start from zero state

    auto issue_tile = [&](float4* dst, int t0) {
#pragma unroll
        for (int k = 0; k < TK; ++k)
            gload_lds16(gl + (size_t)(k * 16) * T_LEN + t0, dst + k * WPC);
    };

    // prologue: fill 3 of the 4 ring slots (12 loads in flight)
    issue_tile(&buf[0][0], t_warm);
    issue_tile(&buf[1][0], t_warm + TK);
    issue_tile(&buf[2][0], t_warm + 2 * TK);

    const int rbase = l * TK;                  // own chain's row base (float4 units)
    const int rx    = (l >> 1) & 3;            // read-side XOR

    int p = 0;
    for (int t0 = t_warm; t0 < t_end; t0 += TK, p = (p + 1) & 3) {
        const int t_pre = t0 + 3 * TK;
        if (t_pre < t_end) {
            issue_tile(&buf[(p + 3) & 3][0], t_pre);      // keep 3 tiles ahead
            asm volatile("s_waitcnt vmcnt(12)" ::: "memory");
        } else {
            const int nrem = (t_end - t0) >> 2;           // tiles incl current: 1..3
            if (nrem == 3)      asm volatile("s_waitcnt vmcnt(8)" ::: "memory");
            else if (nrem == 2) asm volatile("s_waitcnt vmcnt(4)" ::: "memory");
            else                asm volatile("s_waitcnt vmcnt(0)" ::: "memory");
        }
        __builtin_amdgcn_sched_barrier(0);

        const float4* bp = &buf[p][0];
        float4 x[TK];
#pragma unroll
        for (int s = 0; s < TK; ++s)
            x[s] = bp[rbase + (s ^ rx)];

        if (t0 < t_start) {                    // warm-up: state only
#pragma unroll
            for (int s = 0; s < TK; ++s) step_one<false>(pr, x[s], sms, gw, rs);
        } else {                               // output phase
            float q[TK];
#pragma unroll
            for (int s = 0; s < TK; ++s) q[s] = step_one<true>(pr, x[s], sms, gw, rs);
            float4 w;
            w.x = q[0]; w.y = q[1]; w.z = q[2]; w.w = q[3];
            qout[t0 / 4] = w;
        }
    }

    if (chunk == NCHUNK - 1) {                 // final state for the t==0 fix-up
        ws[chain * 2 + 0] = sms;
        ws[chain * 2 + 1] = gw;
    }
}

// ---------------- t == 0 fix-up kernel ----------------
// Q[b,0] uses SMS1=final sms, GW1=final gw, RS=rs after step 0 (exact: zero start state).
__global__ __launch_bounds__(256)
void hirnn_t0_kernel(const float* __restrict__ inp,
                     const float* __restrict__ pINSC, const float* __restrict__ pCOEFF,
                     const float* __restrict__ pSQ,   const float* __restrict__ pSMSC,
                     const float* __restrict__ pSUB,  const float* __restrict__ pCRAK,
                     const float* __restrict__ pRecK, const float* __restrict__ pKr,
                     const float* __restrict__ pLG,   const float* __restrict__ pLS,
                     const float* __restrict__ ws, float* __restrict__ out)
{
    const int b = blockIdx.x * blockDim.x + threadIdx.x;
    if (b >= NCH) return;

    const Params pr = mkparams(pINSC, pCOEFF, pSQ, pSMSC, pSUB, pCRAK, pRecK, pKr, pLG, pLS);

    const float4 x0 = reinterpret_cast<const float4*>(inp)[(size_t)b * T_LEN];
    const float p = x0.x, pet = x0.y, rsmax = x0.z, area = x0.w;

    const float INT = fminf(fminf(pr.insc, pet), p);
    const float INR = p - INT;

    // RS after step 0, exact from zero state: sms=0 -> ratio=0, infil=C; gw=0 -> BAS0=0
    const float RMO0   = fminf(pr.C, INR);
    const float IRUN0  = INR - RMO0;
    const float infl0  = IRUN0 * area;
    const float xr0    = infl0 - rsmax;
    const float Qor0   = fmaxf(xr0, 0.f);
    const float Qir0   = (xr0 > 0.f) ? (pr.kr * rsmax) : 0.f;   // rs=0 -> power term = 0
    const float rs0    = infl0 - Qor0 - Qir0;

    // post-pass with SMS1 = final sms, GW1 = final gw
    const float smsF  = ws[b * 2 + 0];
    const float gwF   = ws[b * 2 + 1];
    const float smsc  = fminf(fmaxf(smsF, 0.f), pr.S);
    const float ratio = smsc * pr.invS;
    const float infil = pr.C * __expf(pr.eca * smsc);
    const float RMO   = fminf(infil, INR);
    const float IRUN  = INR - RMO;
    const float SRUN  = pr.sub * ratio * RMO;
    const float BAS   = pr.rk * fmaxf(gwF, 0.f);

    const float inflow = (IRUN + SRUN + BAS) * area;
    const float rinv   = __builtin_amdgcn_rcpf(rsmax);
    const float xq     = (rs0 + inflow) - rsmax;
    const float Qor2   = fmaxf(xq, 0.f);
    const float r2     = rs0 * rinv;
    const float Qir2   = (xq > 0.f) ? (pr.kr * rsmax)
                                    : (pr.kr * rs0 * (r2 * __builtin_amdgcn_sqrtf(r2)));
    const float oma    = 1.f - area;
    const float dra    = (SRUN + IRUN) * oma + Qir2 + Qor2 - pr.ls;
    out[(size_t)b * T_LEN] = fmaxf(fmaxf(dra, 0.f) + BAS * oma, 0.f);
}

extern "C" void kernel_launch(void* const* d_in, const int* in_sizes, int n_in,
                              void* d_out, int out_size, void* d_ws, size_t ws_size,
                              hipStream_t stream) {
    const float* inp = (const float*)d_in[0];
    float* out = (float*)d_out;
    float* ws  = (float*)d_ws;   // 4096 * 2 floats

    const int blocks = NCHUNK * (NCH / WPC);    // 32 x 64 = 2048 blocks, 1 wave each
    hirnn_chunk_kernel<<<blocks, WPC, 0, stream>>>(
        inp,
        (const float*)d_in[1], (const float*)d_in[2], (const float*)d_in[3],
        (const float*)d_in[4], (const float*)d_in[5], (const float*)d_in[6],
        (const float*)d_in[7], (const float*)d_in[8], (const float*)d_in[9],
        (const float*)d_in[10],
        out, ws);

    hirnn_t0_kernel<<<NCH / 256, 256, 0, stream>>>(
        inp,
        (const float*)d_in[1], (const float*)d_in[2], (const float*)d_in[3],
        (const float*)d_in[4], (const float*)d_in[5], (const float*)d_in[6],
        (const float*)d_in[7], (const float*)d_in[8], (const float*)d_in[9],
        (const float*)d_in[10],
        ws, out);
}

// Round 6
// 289.701 us; speedup vs baseline: 1.2248x; 1.0885x over previous
//
#include <hip/hip_runtime.h>

#define T_LEN  2048
#define NCH    4096     // chains (B)
#define CH     128      // chunk length (timesteps per output chunk)
#define NCHUNK (T_LEN / CH)
#define WARM   256      // warm-up steps before each chunk (chunks 0-1: exact from zero)
#define TK     8        // timesteps per LDS tile (8 KB per tile)
#define NBUF   4        // ring depth: 32 KB LDS -> 4 blocks/CU (grid = 1024, fully resident)
#define WPC    64       // chains per wave (= block size, 1 wave per block)

__device__ __forceinline__ float clampf(float x, float lo, float hi) {
    return fminf(fmaxf(x, lo), hi);
}

struct Params {
    float insc, C, S, sub, crak, rk, kr, lg, ls, invS, eca;
};

__device__ __forceinline__ Params mkparams(
    const float* pINSC, const float* pCOEFF, const float* pSQ, const float* pSMSC,
    const float* pSUB, const float* pCRAK, const float* pRecK, const float* pKr,
    const float* pLG, const float* pLS)
{
    Params pr;
    pr.insc = clampf(pINSC[0] * 5.f,   0.5f,   5.f);
    pr.C    = clampf(pCOEFF[0] * 400.f, 50.f,  400.f);
    float q = clampf(pSQ[0] * 6.f,     0.f,    6.f);
    pr.S    = clampf(pSMSC[0] * 500.f, 50.f,   500.f);
    pr.sub  = clampf(pSUB[0],          0.f,    1.f);
    pr.crak = clampf(pCRAK[0],         0.f,    1.f);
    pr.rk   = clampf(pRecK[0] * 0.3f,  0.003f, 0.3f);
    pr.kr   = clampf(pKr[0] * 0.1f,    0.01f,  0.1f);
    pr.lg   = clampf(pLG[0] * 0.1f,    0.001f, 0.1f);
    pr.ls   = clampf(pLS[0] * 10.f,    0.01f,  10.f);
    pr.invS = 1.0f / pr.S;
    pr.eca  = -q * pr.invS;
    return pr;
}

// HBM -> LDS direct (no VGPR round trip). LDS dest is wave-uniform base;
// HW writes lane i at dst + i*16. Global src address is per-lane.
__device__ __forceinline__ void gload_lds16(const float4* g, float4* l) {
    __builtin_amdgcn_global_load_lds(
        (const __attribute__((address_space(1))) void*)(g),
        (__attribute__((address_space(3))) void*)(l),
        16, 0, 0);
}

// One recurrence step. OUT=true additionally computes the fused post-pass Q.
template <bool OUT>
__device__ __forceinline__ float step_one(const Params& pr, const float4& xv,
                                          float& sms, float& gw, float& rs)
{
    const float p = xv.x, pet = xv.y, rsmax = xv.z, area = xv.w;

    const float INT  = fminf(fminf(pr.insc, pet), p);
    const float INR  = p - INT;
    const float smsc  = fminf(fmaxf(sms, 0.f), pr.S);
    const float ratio = smsc * pr.invS;
    const float infil = pr.C * __expf(pr.eca * smsc);
    const float RMO   = fminf(infil, INR);
    const float IRUN  = INR - RMO;
    const float SRUN  = pr.sub * ratio * RMO;
    const float REC   = pr.crak * ratio * (RMO - SRUN);
    const float SMF   = (RMO - SRUN) - REC;
    const float POT   = pet - INT;              // INT <= pet always -> max(.,0) redundant
    const float ETS   = fminf(POT, 10.f * ratio);
    const float nsms  = smsc + (SMF - ETS);
    const float RECn  = REC + fmaxf(nsms - pr.S, 0.f);
    const float BAS   = pr.rk * fmaxf(gw, 0.f);
    const float ngw   = (gw - pr.lg) + (RECn - BAS);
    const float inflow = (IRUN + SRUN + BAS) * area;
    const float rinv   = __builtin_amdgcn_rcpf(rsmax);
    const float xr     = (rs + inflow) - rsmax;
    const float Qor    = fmaxf(xr, 0.f);
    const float rrt    = rs * rinv;
    const float Qir    = (xr > 0.f) ? (pr.kr * rsmax)
                                    : (pr.kr * rs * (rrt * __builtin_amdgcn_sqrtf(rrt)));
    const float nrs    = rs + ((inflow - Qor) - Qir);

    float q = 0.f;
    if constexpr (OUT) {
        // fused post-pass (valid for t>=1; t==0 fixed by hirnn_t0_kernel)
        const float xq   = (nrs + inflow) - rsmax;
        const float Qor2 = fmaxf(xq, 0.f);
        const float r2   = nrs * rinv;
        const float Qir2 = (xq > 0.f) ? (pr.kr * rsmax)
                                      : (pr.kr * nrs * (r2 * __builtin_amdgcn_sqrtf(r2)));
        const float oma  = 1.f - area;
        const float dra  = (SRUN + IRUN) * oma + Qir2 + Qor2 - pr.ls;
        q = fmaxf(fmaxf(dra, 0.f) + BAS * oma, 0.f);
    }

    sms = nsms; gw = ngw; rs = nrs;
    return q;
}

// ---------------- main chunked scan kernel ----------------
// CH=128: 16 chunks x 64 chain-groups = 1024 one-wave blocks (4/CU, 1 wave/SIMD).
// Total work = 368,640 wave-steps (60% of the CH=64 design); every output's
// effective warm-up stays >= 256 steps (accuracy unchanged vs CH=64/WARM=256).
//
// Per 8-step tile the wave stages [64 chains x 8 steps] HBM->LDS via 8
// global_load_lds (8 contiguous 128B segments each), 4-deep ring, counted
// s_waitcnt vmcnt keeping 3 tiles (24 loads) in flight. No __syncthreads.
//
// Block decode: blk = chunk*64 + cgrp -> chunks of one group are spaced 64
// apart (same XCD mod 8) so overlapping warm-up windows share L2 (R4 lesson).
//
// Step index XOR-swizzled on the GLOBAL source address (LDS dest is linear):
// slot (chain c, j) holds step j ^ (c&7) -> per-step wave ds_read_b128 spreads
// across all bank-quads.
__global__ __launch_bounds__(64)
void hirnn_chunk_kernel(const float* __restrict__ inp,
                        const float* __restrict__ pINSC, const float* __restrict__ pCOEFF,
                        const float* __restrict__ pSQ,   const float* __restrict__ pSMSC,
                        const float* __restrict__ pSUB,  const float* __restrict__ pCRAK,
                        const float* __restrict__ pRecK, const float* __restrict__ pKr,
                        const float* __restrict__ pLG,   const float* __restrict__ pLS,
                        float* __restrict__ out, float* __restrict__ ws)
{
    __shared__ float4 buf[NBUF][WPC * TK];     // 4 x 8 KB = 32 KB

    const int l     = threadIdx.x;             // lane 0..63
    const int blk   = blockIdx.x;
    const int chunk = blk >> 6;                // 64 chain-groups per chunk
    const int cgrp  = blk & 63;
    const int cbase = cgrp * WPC;
    const int chain = cbase + l;

    const Params pr = mkparams(pINSC, pCOEFF, pSQ, pSMSC, pSUB, pCRAK, pRecK, pKr, pLG, pLS);

    // Staging map, instruction k (k=0..7): lane l covers
    //   chain = cbase + 8k + (l>>3), global step = t0 + ((l&7) ^ (l>>3))
    // -> 8 contiguous 128B segments per instruction.
    const int row  = l >> 3;                   // 0..7
    const int scol = l & 7;
    const float4* __restrict__ gl =
        reinterpret_cast<const float4*>(inp) + (size_t)(cbase + row) * T_LEN + (scol ^ row);

    float4* __restrict__ qout = reinterpret_cast<float4*>(out + (size_t)chain * T_LEN);

    const int t_start = chunk * CH;
    const int t_warm  = (t_start >= WARM) ? (t_start - WARM) : 0;
    const int t_end   = t_start + CH;

    float sms = 0.f, gw = 0.f, rs = 0.f;       // warm-start from zero state

    auto issue_tile = [&](float4* dst, int t0) {
#pragma unroll
        for (int k = 0; k < TK; ++k)
            gload_lds16(gl + (size_t)(k * 8) * T_LEN + t0, dst + k * WPC);
    };

    // prologue: fill 3 of the 4 ring slots (24 loads in flight)
    issue_tile(&buf[0][0], t_warm);
    issue_tile(&buf[1][0], t_warm + TK);
    issue_tile(&buf[2][0], t_warm + 2 * TK);

    const int rbase = l * TK;                  // own chain's row base (float4 units)
    const int rx    = l & 7;                   // read-side XOR

    int p = 0;
    for (int t0 = t_warm; t0 < t_end; t0 += TK, p = (p + 1) & 3) {
        const int t_pre = t0 + 3 * TK;
        if (t_pre < t_end) {
            issue_tile(&buf[(p + 3) & 3][0], t_pre);      // keep 3 tiles ahead
            asm volatile("s_waitcnt vmcnt(24)" ::: "memory");
        } else {
            const int nrem = (t_end - t0) >> 3;           // tiles incl current: 1..3
            if (nrem == 3)      asm volatile("s_waitcnt vmcnt(16)" ::: "memory");
            else if (nrem == 2) asm volatile("s_waitcnt vmcnt(8)" ::: "memory");
            else                asm volatile("s_waitcnt vmcnt(0)" ::: "memory");
        }
        __builtin_amdgcn_sched_barrier(0);

        const float4* bp = &buf[p][0];
        float4 x[TK];
#pragma unroll
        for (int s = 0; s < TK; ++s)
            x[s] = bp[rbase + (s ^ rx)];

        if (t0 < t_start) {                    // warm-up: state only
#pragma unroll
            for (int s = 0; s < TK; ++s) step_one<false>(pr, x[s], sms, gw, rs);
        } else {                               // output phase
            float q[TK];
#pragma unroll
            for (int s = 0; s < TK; ++s) q[s] = step_one<true>(pr, x[s], sms, gw, rs);
            float4 w0, w1;
            w0.x = q[0]; w0.y = q[1]; w0.z = q[2]; w0.w = q[3];
            w1.x = q[4]; w1.y = q[5]; w1.z = q[6]; w1.w = q[7];
            qout[t0 / 4 + 0] = w0;
            qout[t0 / 4 + 1] = w1;
        }
    }

    if (chunk == NCHUNK - 1) {                 // final state for the t==0 fix-up
        ws[chain * 2 + 0] = sms;
        ws[chain * 2 + 1] = gw;
    }
}

// ---------------- t == 0 fix-up kernel ----------------
// Q[b,0] uses SMS1=final sms, GW1=final gw, RS=rs after step 0 (exact: zero start state).
__global__ __launch_bounds__(256)
void hirnn_t0_kernel(const float* __restrict__ inp,
                     const float* __restrict__ pINSC, const float* __restrict__ pCOEFF,
                     const float* __restrict__ pSQ,   const float* __restrict__ pSMSC,
                     const float* __restrict__ pSUB,  const float* __restrict__ pCRAK,
                     const float* __restrict__ pRecK, const float* __restrict__ pKr,
                     const float* __restrict__ pLG,   const float* __restrict__ pLS,
                     const float* __restrict__ ws, float* __restrict__ out)
{
    const int b = blockIdx.x * blockDim.x + threadIdx.x;
    if (b >= NCH) return;

    const Params pr = mkparams(pINSC, pCOEFF, pSQ, pSMSC, pSUB, pCRAK, pRecK, pKr, pLG, pLS);

    const float4 x0 = reinterpret_cast<const float4*>(inp)[(size_t)b * T_LEN];
    const float p = x0.x, pet = x0.y, rsmax = x0.z, area = x0.w;

    const float INT = fminf(fminf(pr.insc, pet), p);
    const float INR = p - INT;

    // RS after step 0, exact from zero state: sms=0 -> ratio=0, infil=C; gw=0 -> BAS0=0
    const float RMO0   = fminf(pr.C, INR);
    const float IRUN0  = INR - RMO0;
    const float infl0  = IRUN0 * area;
    const float xr0    = infl0 - rsmax;
    const float Qor0   = fmaxf(xr0, 0.f);
    const float Qir0   = (xr0 > 0.f) ? (pr.kr * rsmax) : 0.f;   // rs=0 -> power term = 0
    const float rs0    = infl0 - Qor0 - Qir0;

    // post-pass with SMS1 = final sms, GW1 = final gw
    const float smsF  = ws[b * 2 + 0];
    const float gwF   = ws[b * 2 + 1];
    const float smsc  = fminf(fmaxf(smsF, 0.f), pr.S);
    const float ratio = smsc * pr.invS;
    const float infil = pr.C * __expf(pr.eca * smsc);
    const float RMO   = fminf(infil, INR);
    const float IRUN  = INR - RMO;
    const float SRUN  = pr.sub * ratio * RMO;
    const float BAS   = pr.rk * fmaxf(gwF, 0.f);

    const float inflow = (IRUN + SRUN + BAS) * area;
    const float rinv   = __builtin_amdgcn_rcpf(rsmax);
    const float xq     = (rs0 + inflow) - rsmax;
    const float Qor2   = fmaxf(xq, 0.f);
    const float r2     = rs0 * rinv;
    const float Qir2   = (xq > 0.f) ? (pr.kr * rsmax)
                                    : (pr.kr * rs0 * (r2 * __builtin_amdgcn_sqrtf(r2)));
    const float oma    = 1.f - area;
    const float dra    = (SRUN + IRUN) * oma + Qir2 + Qor2 - pr.ls;
    out[(size_t)b * T_LEN] = fmaxf(fmaxf(dra, 0.f) + BAS * oma, 0.f);
}

extern "C" void kernel_launch(void* const* d_in, const int* in_sizes, int n_in,
                              void* d_out, int out_size, void* d_ws, size_t ws_size,
                              hipStream_t stream) {
    const float* inp = (const float*)d_in[0];
    float* out = (float*)d_out;
    float* ws  = (float*)d_ws;   // 4096 * 2 floats

    const int blocks = NCHUNK * (NCH / WPC);    // 16 x 64 = 1024 blocks, 1 wave each
    hirnn_chunk_kernel<<<blocks, WPC, 0, stream>>>(
        inp,
        (const float*)d_in[1], (const float*)d_in[2], (const float*)d_in[3],
        (const float*)d_in[4], (const float*)d_in[5], (const float*)d_in[6],
        (const float*)d_in[7], (const float*)d_in[8], (const float*)d_in[9],
        (const float*)d_in[10],
        out, ws);

    hirnn_t0_kernel<<<NCH / 256, 256, 0, stream>>>(
        inp,
        (const float*)d_in[1], (const float*)d_in[2], (const float*)d_in[3],
        (const float*)d_in[4], (const float*)d_in[5], (const float*)d_in[6],
        (const float*)d_in[7], (const float*)d_in[8], (const float*)d_in[9],
        (const float*)d_in[10],
        ws, out);
}